// Round 1
// baseline (170.427 us; speedup 1.0000x reference)
//
#include <hip/hip_runtime.h>
#include <math.h>

// GroupLoss: preds (16,8,17,128,128) f32, gt (16,8,10,17,2) f32
// -> (total_within, total_across) two f32 scalars.
// N=128 flattened batch, P=10 persons, K=17 keypoints, H=W=128, stride=4.

constexpr int N = 128;
constexpr int P = 10;
constexpr int K = 17;
constexpr int H = 128;
constexpr int W = 128;
constexpr float INV_STRIDE = 0.25f;   // 1/FEAT_STRIDE, exact

// One block (1 wave of 64) per n. Lanes 0..9 each own a person:
// 17 independent gathers per lane -> MLP hides HBM-miss latency.
__global__ __launch_bounds__(64) void group_loss_per_n(
    const float* __restrict__ preds,
    const float* __restrict__ gt,
    float* __restrict__ ws)   // ws[0..127]=within_n, ws[128..255]=across_n
{
    const int n = blockIdx.x;
    const int lane = threadIdx.x;

    __shared__ float s_within[P];
    __shared__ float s_embed[P];
    __shared__ float s_pvalid[P];

    if (lane < P) {
        const int p = lane;
        const float* g  = gt + ((size_t)(n * P + p)) * (K * 2);
        const float* pr = preds + (size_t)n * (K * H * W);

        float vals[K];
        float msk[K];
        float s = 0.f, c = 0.f;
        #pragma unroll
        for (int k = 0; k < K; ++k) {
            const float gx = g[2 * k + 0];
            const float gy = g[2 * k + 1];
            // jnp.round == round half-to-even == rintf (default RNE)
            const int x = (int)rintf(gx * INV_STRIDE);
            const int y = (int)rintf(gy * INV_STRIDE);
            const bool v = (x >= 0) & (x < W) & (y >= 0) & (y < H);
            const int xc = min(max(x, 0), W - 1);
            const int yc = min(max(y, 0), H - 1);
            const float val = pr[k * H * W + yc * W + xc];
            const float m = v ? 1.f : 0.f;
            vals[k] = val;
            msk[k]  = m;
            s += val * m;
            c += m;
        }
        const float safe  = fmaxf(c, 1.f);
        const float embed = s / safe;
        float wp = 0.f;
        #pragma unroll
        for (int k = 0; k < K; ++k) {
            const float d = vals[k] - embed;
            wp += d * d * msk[k];
        }
        wp = (c > 0.f) ? (wp / safe) : 0.f;
        s_within[p] = wp;
        s_embed[p]  = embed;
        s_pvalid[p] = (c > 0.f) ? 1.f : 0.f;
    }
    __syncthreads();

    if (lane == 0) {
        float within = 0.f;
        for (int p = 0; p < P; ++p) within += s_within[p];
        within *= (1.f / (float)P);

        float hinge = 0.f, denom = 0.f;
        for (int i = 0; i < P; ++i) {
            for (int j = 0; j < P; ++j) {
                if (i == j) continue;
                const float pair = s_pvalid[i] * s_pvalid[j];
                const float d = fabsf(s_embed[j] - s_embed[i]);
                hinge += fmaxf(1.f - d, 0.f) * pair;
                denom += pair;
            }
        }
        const float across = (denom > 0.f) ? (hinge / fmaxf(denom, 1.f)) : 0.f;
        ws[n]     = within;
        ws[N + n] = across;
    }
}

// Single-wave final reduction over the 128 per-n partials.
__global__ __launch_bounds__(64) void group_loss_reduce(
    const float* __restrict__ ws, float* __restrict__ out)
{
    const int t = threadIdx.x;  // 64 threads
    float w = ws[t]     + ws[t + 64];
    float a = ws[N + t] + ws[N + t + 64];
    #pragma unroll
    for (int off = 32; off > 0; off >>= 1) {
        w += __shfl_down(w, off);
        a += __shfl_down(a, off);
    }
    if (t == 0) {
        out[0] = w * (1.f / (float)N);   // total_within (W_WITHIN = 1)
        out[1] = a * (1.f / (float)N);   // total_across (W_ACROSS = 1)
    }
}

extern "C" void kernel_launch(void* const* d_in, const int* in_sizes, int n_in,
                              void* d_out, int out_size, void* d_ws, size_t ws_size,
                              hipStream_t stream) {
    const float* preds = (const float*)d_in[0];  // 16*8*17*128*128
    const float* gt    = (const float*)d_in[1];  // 16*8*10*17*2
    float* out = (float*)d_out;                  // 2 floats
    float* ws  = (float*)d_ws;                   // needs 256 floats

    group_loss_per_n<<<N, 64, 0, stream>>>(preds, gt, ws);
    group_loss_reduce<<<1, 64, 0, stream>>>(ws, out);
}